// Round 6
// baseline (70.898 us; speedup 1.0000x reference)
//
#include <hip/hip_runtime.h>
#include <hip/hip_bf16.h>

#define DD 256
#define NN 8192
#define B_ROWS 4096
#define NRG 32                 // row-groups of 256
#define NCJ 64                 // col-chunks of 128
#define NBLK 1056              // sum_{rg} (64 - 2*rg)
#define M_FIX 160.0f           // fixed softmax offset (exp2 domain)
#define SCALE 1.6986436f       // sqrt(2*log2(e)): sim lands in exp2 domain
#define LN2 0.69314718055994531f

typedef __attribute__((ext_vector_type(8))) short bf16x8;
typedef __attribute__((ext_vector_type(4))) float f32x4;

__device__ __forceinline__ unsigned short f2bf(float f) {
    unsigned int x = __float_as_uint(f);
    x += 0x7fffu + ((x >> 16) & 1u);   // RNE
    return (unsigned short)(x >> 16);
}
__device__ __forceinline__ float bf2f(unsigned short u) {
    return __uint_as_float((unsigned int)u << 16);
}
__device__ __forceinline__ float exp2_raw(float x) {
    float r; asm("v_exp_f32 %0, %1" : "=v"(r) : "v"(x)); return r;
}
__device__ __forceinline__ void gload16(const unsigned short* g, unsigned short* l) {
    __builtin_amdgcn_global_load_lds(
        (const __attribute__((address_space(1))) void*)g,
        (__attribute__((address_space(3))) void*)l, 16, 0, 0);
}

// ------------- Kernel 1: fused cast(z*SCALE -> bf16) + pos dot (fp32) --------
__global__ void cast_pos_kernel(const float* __restrict__ zi, const float* __restrict__ zj,
                                unsigned short* __restrict__ zb, float* __restrict__ pos) {
    const int w = threadIdx.x >> 6;
    const int l = threadIdx.x & 63;
    const int r = blockIdx.x * 4 + w;                       // grid 1024 -> r < 4096
    const float4 a = ((const float4*)(zi + (size_t)r * DD))[l];
    const float4 b = ((const float4*)(zj + (size_t)r * DD))[l];
    float d = a.x * b.x + a.y * b.y + a.z * b.z + a.w * b.w;
    #pragma unroll
    for (int off = 32; off > 0; off >>= 1) d += __shfl_down(d, off, 64);
    if (l == 0) pos[r] = 2.0f * d;                          // natural-domain pos logit
    ushort4 oa, ob;
    oa.x = f2bf(a.x * SCALE); oa.y = f2bf(a.y * SCALE);
    oa.z = f2bf(a.z * SCALE); oa.w = f2bf(a.w * SCALE);
    ob.x = f2bf(b.x * SCALE); ob.y = f2bf(b.y * SCALE);
    ob.z = f2bf(b.z * SCALE); ob.w = f2bf(b.w * SCALE);
    ((ushort4*)(zb + (size_t)r * DD))[l] = oa;
    ((ushort4*)(zb + (size_t)(r + B_ROWS) * DD))[l] = ob;
}

// ------------- Kernel 2: symmetric Gram + fixed-M exp2 sums, dbuf ------------
// grid: 1056 rect blocks (rg: 256 rows) x (cj: 128 cols), cj >= 2*rg.
// cj in {2rg, 2rg+1}: diagonal square halves — row-sums only, i==j masked.
// cj >= 2rg+2: strictly above diagonal — row-sums + mirror col-sums.
// block: 256 thr = 4 waves; wave owns 64 rows (aF[4][8] = 128 VGPR, R=4 reuse).
// Cols staged as 32-col chunks in MFMA fragment order, double-buffered,
// one barrier per chunk (stage issued before compute -> latency hidden).
// PT bf16 [64][NN]: row partials at PT[cj][row], mirror partials at PT[2rg][col].
__global__ __launch_bounds__(256, 2) void simlse_kernel(const unsigned short* __restrict__ zb,
                                                        unsigned short* __restrict__ PT) {
    __shared__ unsigned short tile[2][16 * 512];            // 2 x 16 KB
    const int tid = threadIdx.x;
    const int w  = tid >> 6;        // 0..3
    const int l  = tid & 63;
    const int lg = l >> 4;          // 0..3
    const int lr = l & 15;          // 0..15

    // XCD-aware bijective swizzle (1056 = 8 x 132)
    const int wg = ((int)blockIdx.x & 7) * (NBLK / 8) + ((int)blockIdx.x >> 3);
    int b = wg, rg = 0;
    while (b >= NCJ - 2 * rg) { b -= NCJ - 2 * rg; ++rg; }
    const int cj = 2 * rg + b;
    const bool mirror = (cj >= 2 * rg + 2);                 // block-uniform
    const int rbase = rg * 256 + w * 64;
    const int cbase = cj * 128;
    const int ri_u0 = rg * 16 + w * 4;                      // wave's first row-tile (16-units)

    // A fragments: 4 row-tiles x 8 k-slices (128 VGPR)
    bf16x8 aF[4][8];
    #pragma unroll
    for (int rt = 0; rt < 4; ++rt) {
        const unsigned short* ap = zb + (size_t)(rbase + rt * 16 + lr) * DD + lg * 8;
        #pragma unroll
        for (int ks = 0; ks < 8; ++ks) aF[rt][ks] = *(const bf16x8*)(ap + ks * 32);
    }

    float rs[4][4];
    #pragma unroll
    for (int rt = 0; rt < 4; ++rt)
        #pragma unroll
        for (int j = 0; j < 4; ++j) rs[rt][j] = 0.f;
    float cs[8];
    #pragma unroll
    for (int ct = 0; ct < 8; ++ct) cs[ct] = 0.f;

    // prologue: stage chunk 0 into buf 0 (wave w fills slots w*4..w*4+3)
    #pragma unroll
    for (int jj = 0; jj < 4; ++jj) {
        const int slot = w * 4 + jj, sl = slot >> 3, ks = slot & 7;
        gload16(zb + (size_t)(cbase + sl * 16 + lr) * DD + ks * 32 + lg * 8,
                &tile[0][slot * 512]);
    }
    __syncthreads();                                        // drain chunk-0 loads

    for (int c = 0; c < 4; ++c) {
        if (c < 3) {                                        // prefetch next chunk
            const int c1 = cbase + (c + 1) * 32;
            #pragma unroll
            for (int jj = 0; jj < 4; ++jj) {
                const int slot = w * 4 + jj, sl = slot >> 3, ks = slot & 7;
                gload16(zb + (size_t)(c1 + sl * 16 + lr) * DD + ks * 32 + lg * 8,
                        &tile[(c + 1) & 1][slot * 512]);
            }
        }
        const unsigned short* buf = tile[c & 1];
        #pragma unroll
        for (int sl = 0; sl < 2; ++sl) {
            const int ct = c * 2 + sl;                      // block col-tile 0..7
            f32x4 acc[4];
            #pragma unroll
            for (int rt = 0; rt < 4; ++rt) acc[rt] = (f32x4){0.f, 0.f, 0.f, 0.f};
            #pragma unroll
            for (int ks = 0; ks < 8; ++ks) {
                bf16x8 bF = *(const bf16x8*)(buf + (sl * 8 + ks) * 512 + l * 8);
                #pragma unroll
                for (int rt = 0; rt < 4; ++rt)
                    acc[rt] = __builtin_amdgcn_mfma_f32_16x16x32_bf16(aF[rt][ks], bF, acc[rt], 0, 0, 0);
            }
            const int ci_u = cj * 8 + ct;
            #pragma unroll
            for (int rt = 0; rt < 4; ++rt) {
                const bool dt = (!mirror) && (ri_u0 + rt == ci_u);
                #pragma unroll
                for (int j = 0; j < 4; ++j) {
                    float e = exp2_raw(acc[rt][j] - M_FIX);
                    if (dt && (lr == lg * 4 + j)) e = 0.f;  // mask i==j
                    rs[rt][j] += e;
                    cs[ct] += e;
                }
            }
        }
        __syncthreads();        // my prefetch arrived (vmcnt0) + all reads of buf done
    }

    // row sums: reduce over 16 lanes sharing lg; lr==0 lanes write
    #pragma unroll
    for (int rt = 0; rt < 4; ++rt)
        #pragma unroll
        for (int j = 0; j < 4; ++j) {
            float v = rs[rt][j];
            v += __shfl_xor(v, 1, 64);
            v += __shfl_xor(v, 2, 64);
            v += __shfl_xor(v, 4, 64);
            v += __shfl_xor(v, 8, 64);
            rs[rt][j] = v;
        }
    if (lr == 0) {
        #pragma unroll
        for (int rt = 0; rt < 4; ++rt)
            #pragma unroll
            for (int j = 0; j < 4; ++j)
                PT[(size_t)cj * NN + rbase + rt * 16 + lg * 4 + j] = f2bf(rs[rt][j]);
    }

    // mirror column sums -> slot 2*rg (strictly-above blocks only; block-uniform)
    if (mirror) {
        #pragma unroll
        for (int ct = 0; ct < 8; ++ct) {
            float v = cs[ct];
            v += __shfl_xor(v, 16, 64);
            v += __shfl_xor(v, 32, 64);
            cs[ct] = v;                                     // sum over wave's 64 rows
        }
        float* red = (float*)tile;                          // [4][128] floats = 2 KB
        if (lg == 0) {
            #pragma unroll
            for (int ct = 0; ct < 8; ++ct) red[w * 128 + ct * 16 + lr] = cs[ct];
        }
        __syncthreads();
        if (tid < 128) {
            const float v = red[tid] + red[128 + tid] + red[256 + tid] + red[384 + tid];
            PT[(size_t)(2 * rg) * NN + cbase + tid] = f2bf(v);
        }
    }
}

// ------------- Kernel 3: per-row masked-slot sum + pos subtraction -----------
__global__ void rowmerge_kernel(const unsigned short* __restrict__ PT,
                                const float* __restrict__ pos, float* __restrict__ partial) {
    const int r = blockIdx.x * 256 + threadIdx.x;           // grid 32 -> r < 8192
    const int rg = r >> 8;                                  // block-uniform
    float S = 0.f;
    for (int s = 2 * rg; s < NCJ; ++s) S += bf2f(PT[(size_t)s * NN + r]);   // row slots
    for (int s = 0; s < 2 * rg; s += 2) S += bf2f(PT[(size_t)s * NN + r]);  // mirror slots
    float val = M_FIX * LN2 + logf(S);                      // natural-domain lse
    if (r < B_ROWS) val -= 2.0f * pos[r];                   // both halves' pos
    __shared__ float red[256];
    red[threadIdx.x] = val;
    __syncthreads();
    for (int st = 128; st > 0; st >>= 1) {
        if (threadIdx.x < st) red[threadIdx.x] += red[threadIdx.x + st];
        __syncthreads();
    }
    if (threadIdx.x == 0) partial[blockIdx.x] = red[0];
}

// ------------- Kernel 4: final scalar ----------------------------------------
__global__ void final_kernel(const float* __restrict__ partial, float* __restrict__ out) {
    float v = (threadIdx.x < 32) ? partial[threadIdx.x] : 0.f;
    #pragma unroll
    for (int off = 32; off > 0; off >>= 1) v += __shfl_down(v, off, 64);
    if (threadIdx.x == 0) out[0] = v / (8192.f * 8192.f);
}

extern "C" void kernel_launch(void* const* d_in, const int* in_sizes, int n_in,
                              void* d_out, int out_size, void* d_ws, size_t ws_size,
                              hipStream_t stream) {
    const float* zi = (const float*)d_in[0];
    const float* zj = (const float*)d_in[1];
    float* out = (float*)d_out;
    char* ws = (char*)d_ws;

    unsigned short* zb = (unsigned short*)ws;                         // 4 MB
    unsigned short* PT = (unsigned short*)(ws + (size_t)NN * DD * 2); // 1 MB bf16 [64][NN]
    float* pos     = (float*)(ws + (size_t)NN * DD * 2 + (size_t)NCJ * NN * 2);  // 16 KB
    float* partial = pos + B_ROWS;                                    // 128 B
    // total ws footprint: 5.0165 MB (== round-3/5 proven-safe footprint)

    hipLaunchKernelGGL(cast_pos_kernel, dim3(B_ROWS / 4), dim3(256), 0, stream, zi, zj, zb, pos);
    hipLaunchKernelGGL(simlse_kernel,   dim3(NBLK), dim3(256), 0, stream, zb, PT);
    hipLaunchKernelGGL(rowmerge_kernel, dim3(NN / 256), dim3(256), 0, stream, PT, pos, partial);
    hipLaunchKernelGGL(final_kernel,    dim3(1), dim3(64), 0, stream, partial, out);
}

// Round 8
// 62.552 us; speedup vs baseline: 1.1334x; 1.1334x over previous
//
#include <hip/hip_runtime.h>
#include <hip/hip_bf16.h>

#define DD 256
#define NN 8192
#define B_ROWS 4096
#define NRG 32                 // row-groups of 256
#define NCJ 64                 // col-chunks of 128
#define NBLK 1056              // sum_{rg} (64 - 2*rg)
#define M_FIX 160.0f           // fixed softmax offset (exp2 domain)
#define SCALE 1.6986436f       // sqrt(2*log2(e)): sim lands in exp2 domain
#define LN2 0.69314718055994531f

typedef __attribute__((ext_vector_type(8))) short bf16x8;
typedef __attribute__((ext_vector_type(4))) float f32x4;

__device__ __forceinline__ unsigned short f2bf(float f) {
    unsigned int x = __float_as_uint(f);
    x += 0x7fffu + ((x >> 16) & 1u);   // RNE
    return (unsigned short)(x >> 16);
}
__device__ __forceinline__ float bf2f(unsigned short u) {
    return __uint_as_float((unsigned int)u << 16);
}
__device__ __forceinline__ float exp2_raw(float x) {
    float r; asm("v_exp_f32 %0, %1" : "=v"(r) : "v"(x)); return r;
}
__device__ __forceinline__ void gload16(const unsigned short* g, unsigned short* l) {
    __builtin_amdgcn_global_load_lds(
        (const __attribute__((address_space(1))) void*)g,
        (__attribute__((address_space(3))) void*)l, 16, 0, 0);
}

// ------------- Kernel 1: fused cast(z*SCALE -> bf16) + pos dot (fp32) --------
__global__ void cast_pos_kernel(const float* __restrict__ zi, const float* __restrict__ zj,
                                unsigned short* __restrict__ zb, float* __restrict__ pos) {
    const int w = threadIdx.x >> 6;
    const int l = threadIdx.x & 63;
    const int r = blockIdx.x * 4 + w;                       // grid 1024 -> r < 4096
    const float4 a = ((const float4*)(zi + (size_t)r * DD))[l];
    const float4 b = ((const float4*)(zj + (size_t)r * DD))[l];
    float d = a.x * b.x + a.y * b.y + a.z * b.z + a.w * b.w;
    #pragma unroll
    for (int off = 32; off > 0; off >>= 1) d += __shfl_down(d, off, 64);
    if (l == 0) pos[r] = 2.0f * d;                          // natural-domain pos logit
    ushort4 oa, ob;
    oa.x = f2bf(a.x * SCALE); oa.y = f2bf(a.y * SCALE);
    oa.z = f2bf(a.z * SCALE); oa.w = f2bf(a.w * SCALE);
    ob.x = f2bf(b.x * SCALE); ob.y = f2bf(b.y * SCALE);
    ob.z = f2bf(b.z * SCALE); ob.w = f2bf(b.w * SCALE);
    ((ushort4*)(zb + (size_t)r * DD))[l] = oa;
    ((ushort4*)(zb + (size_t)(r + B_ROWS) * DD))[l] = ob;
}

// ------------- Kernel 2: symmetric Gram + fixed-M exp2 sums ------------------
// grid: 1056 rect blocks (rg: 256 rows) x (cj: 128 cols), cj >= 2*rg.
// cj in {2rg, 2rg+1}: diagonal square halves — row-sums only, i==j masked.
// cj >= 2rg+2: strictly above diagonal — row-sums + mirror col-sums.
// block: 256 thr = 4 waves; wave owns 64 rows (aF[4][8] = 128 VGPR, R=4 reuse).
// ENTIRE 128-col x 256-K panel (64 KB) staged ONCE via global_load_lds in MFMA
// fragment order -> exactly one barrier in the main path. NOTE: accumulator
// inits to ZERO and M_FIX is subtracted in the exp2 arg — the only form that
// has ever passed (acc-init=-M_FIX NaN'd twice: S3, S6).
// PT bf16 [64][NN]: row partials at PT[cj][row], mirror partials at PT[2rg][col].
__global__ __launch_bounds__(256, 2) void simlse_kernel(const unsigned short* __restrict__ zb,
                                                        unsigned short* __restrict__ PT) {
    __shared__ unsigned short tile[64 * 512];               // 64 KB: 64 slots x 1 KB
    const int tid = threadIdx.x;
    const int w  = tid >> 6;        // 0..3
    const int l  = tid & 63;
    const int lg = l >> 4;          // 0..3
    const int lr = l & 15;          // 0..15

    // XCD-aware bijective swizzle (1056 = 8 x 132)
    const int wg = ((int)blockIdx.x & 7) * (NBLK / 8) + ((int)blockIdx.x >> 3);
    int b = wg, rg = 0;
    while (b >= NCJ - 2 * rg) { b -= NCJ - 2 * rg; ++rg; }
    const int cj = 2 * rg + b;
    const bool mirror = (cj >= 2 * rg + 2);                 // block-uniform
    const int rbase = rg * 256 + w * 64;
    const int cbase = cj * 128;
    const int ri_u0 = rg * 16 + w * 4;                      // wave's first row-tile

    // stage whole B-panel: 64 slots (slot = sl*8+ks), wave w fills 16 slots
    #pragma unroll
    for (int jj = 0; jj < 16; ++jj) {
        const int slot = w * 16 + jj, sl = slot >> 3, ks = slot & 7;
        gload16(zb + (size_t)(cbase + sl * 16 + lr) * DD + ks * 32 + lg * 8,
                tile + slot * 512);
    }

    // A fragments: 4 row-tiles x 8 k-slices (128 VGPR)
    bf16x8 aF[4][8];
    #pragma unroll
    for (int rt = 0; rt < 4; ++rt) {
        const unsigned short* ap = zb + (size_t)(rbase + rt * 16 + lr) * DD + lg * 8;
        #pragma unroll
        for (int ks = 0; ks < 8; ++ks) aF[rt][ks] = *(const bf16x8*)(ap + ks * 32);
    }

    float rs[4][4];
    #pragma unroll
    for (int rt = 0; rt < 4; ++rt)
        #pragma unroll
        for (int j = 0; j < 4; ++j) rs[rt][j] = 0.f;
    float cs[8];
    #pragma unroll
    for (int ct = 0; ct < 8; ++ct) cs[ct] = 0.f;

    __syncthreads();                                        // single staging drain

    #pragma unroll
    for (int sl = 0; sl < 8; ++sl) {
        f32x4 acc[4];
        #pragma unroll
        for (int rt = 0; rt < 4; ++rt)
            acc[rt] = (f32x4){0.f, 0.f, 0.f, 0.f};
        #pragma unroll
        for (int ks = 0; ks < 8; ++ks) {
            bf16x8 bF = *(const bf16x8*)(tile + (sl * 8 + ks) * 512 + l * 8);
            #pragma unroll
            for (int rt = 0; rt < 4; ++rt)
                acc[rt] = __builtin_amdgcn_mfma_f32_16x16x32_bf16(aF[rt][ks], bF, acc[rt], 0, 0, 0);
        }
        const int ci_u = cj * 8 + sl;
        #pragma unroll
        for (int rt = 0; rt < 4; ++rt) {
            const bool dt = (!mirror) && (ri_u0 + rt == ci_u);
            #pragma unroll
            for (int j = 0; j < 4; ++j) {
                float e = exp2_raw(acc[rt][j] - M_FIX);
                if (dt && (lr == lg * 4 + j)) e = 0.f;      // mask i==j
                rs[rt][j] += e;
                cs[sl] += e;
            }
        }
    }

    // row sums: reduce over 16 lanes sharing lg; lr==0 lanes write
    #pragma unroll
    for (int rt = 0; rt < 4; ++rt)
        #pragma unroll
        for (int j = 0; j < 4; ++j) {
            float v = rs[rt][j];
            v += __shfl_xor(v, 1, 64);
            v += __shfl_xor(v, 2, 64);
            v += __shfl_xor(v, 4, 64);
            v += __shfl_xor(v, 8, 64);
            rs[rt][j] = v;
        }
    if (lr == 0) {
        #pragma unroll
        for (int rt = 0; rt < 4; ++rt)
            #pragma unroll
            for (int j = 0; j < 4; ++j)
                PT[(size_t)cj * NN + rbase + rt * 16 + lg * 4 + j] = f2bf(rs[rt][j]);
    }

    // mirror column sums -> slot 2*rg (strictly-above blocks only; block-uniform)
    if (mirror) {
        #pragma unroll
        for (int ct = 0; ct < 8; ++ct) {
            float v = cs[ct];
            v += __shfl_xor(v, 16, 64);
            v += __shfl_xor(v, 32, 64);
            cs[ct] = v;                                     // sum over wave's 64 rows
        }
        __syncthreads();                                    // all tile reads done
        float* red = (float*)tile;                          // [4][128] floats = 2 KB
        if (lg == 0) {
            #pragma unroll
            for (int ct = 0; ct < 8; ++ct) red[w * 128 + ct * 16 + lr] = cs[ct];
        }
        __syncthreads();
        if (tid < 128) {
            const float v = red[tid] + red[128 + tid] + red[256 + tid] + red[384 + tid];
            PT[(size_t)(2 * rg) * NN + cbase + tid] = f2bf(v);
        }
    }
}

// ------------- Kernel 3: per-row masked-slot sum + pos subtraction -----------
// Fixed 64-iteration unrolled loop, branch-free select mask:
// slot s valid for row-group rg iff (s >= 2rg) || s even (provably == the set
// of slots simlse writes for this row). Invalid slots excluded via cndmask.
__global__ __launch_bounds__(128) void rowmerge_kernel(const unsigned short* __restrict__ PT,
                                                       const float* __restrict__ pos,
                                                       float* __restrict__ partial) {
    const int r = blockIdx.x * 128 + threadIdx.x;           // grid 64 -> r < 8192
    const int rg = r >> 8;
    float S = 0.f;
    #pragma unroll
    for (int s = 0; s < NCJ; ++s) {
        const float v = bf2f(PT[(size_t)s * NN + r]);
        const bool valid = (s >= 2 * rg) || ((s & 1) == 0);
        S += valid ? v : 0.f;
    }
    float val = M_FIX * LN2 + logf(S);                      // natural-domain lse
    if (r < B_ROWS) val -= 2.0f * pos[r];                   // both halves' pos
    __shared__ float red[128];
    red[threadIdx.x] = val;
    __syncthreads();
    for (int st = 64; st > 0; st >>= 1) {
        if (threadIdx.x < st) red[threadIdx.x] += red[threadIdx.x + st];
        __syncthreads();
    }
    if (threadIdx.x == 0) partial[blockIdx.x] = red[0];
}

// ------------- Kernel 4: final scalar ----------------------------------------
__global__ void final_kernel(const float* __restrict__ partial, float* __restrict__ out) {
    float v = partial[threadIdx.x];                         // block = 64 = grid of k3
    #pragma unroll
    for (int off = 32; off > 0; off >>= 1) v += __shfl_down(v, off, 64);
    if (threadIdx.x == 0) out[0] = v / (8192.f * 8192.f);
}

extern "C" void kernel_launch(void* const* d_in, const int* in_sizes, int n_in,
                              void* d_out, int out_size, void* d_ws, size_t ws_size,
                              hipStream_t stream) {
    const float* zi = (const float*)d_in[0];
    const float* zj = (const float*)d_in[1];
    float* out = (float*)d_out;
    char* ws = (char*)d_ws;

    unsigned short* zb = (unsigned short*)ws;                         // 4 MB
    unsigned short* PT = (unsigned short*)(ws + (size_t)NN * DD * 2); // 1 MB bf16 [64][NN]
    float* pos     = (float*)(ws + (size_t)NN * DD * 2 + (size_t)NCJ * NN * 2);  // 16 KB
    float* partial = pos + B_ROWS;                                    // 256 B

    hipLaunchKernelGGL(cast_pos_kernel, dim3(B_ROWS / 4), dim3(256), 0, stream, zi, zj, zb, pos);
    hipLaunchKernelGGL(simlse_kernel,   dim3(NBLK), dim3(256), 0, stream, zb, PT);
    hipLaunchKernelGGL(rowmerge_kernel, dim3(NN / 128), dim3(128), 0, stream, PT, pos, partial);
    hipLaunchKernelGGL(final_kernel,    dim3(1), dim3(64), 0, stream, partial, out);
}